// Round 2
// baseline (810.344 us; speedup 1.0000x reference)
//
#include <hip/hip_runtime.h>
#include <cstdint>
#include <cstddef>

#define NN 50000
#define NE 800000
static constexpr int IN_F = 512;
static constexpr int HID  = 256;
static constexpr int OUTF = 128;

// ---------------- graph preprocessing ----------------

__global__ void k_degree(const int* __restrict__ src, const int* __restrict__ dst,
                         int* __restrict__ deg_out, int* __restrict__ deg_in, int E) {
  int e = blockIdx.x * blockDim.x + threadIdx.x;
  if (e < E) {
    atomicAdd(&deg_out[src[e]], 1);
    atomicAdd(&deg_in[dst[e]], 1);
  }
}

__global__ void k_norm(const int* __restrict__ deg_out, const int* __restrict__ deg_in,
                       float* __restrict__ norm_src, float* __restrict__ norm_dst, int N) {
  int i = blockIdx.x * blockDim.x + threadIdx.x;
  if (i < N) {
    int dO = deg_out[i]; if (dO < 1) dO = 1;
    int dI = deg_in[i];  if (dI < 1) dI = 1;
    norm_src[i] = rsqrtf((float)dO);
    norm_dst[i] = rsqrtf((float)dI);
  }
}

__global__ void k_scan1(const int* __restrict__ deg_in, int* __restrict__ excl,
                        int* __restrict__ bsums, int N) {
  __shared__ int s[512];
  int t = threadIdx.x;
  int g = blockIdx.x * 512 + t;
  int v = (g < N) ? deg_in[g] : 0;
  s[t] = v;
  __syncthreads();
  for (int off = 1; off < 512; off <<= 1) {
    int add = (t >= off) ? s[t - off] : 0;
    __syncthreads();
    s[t] += add;
    __syncthreads();
  }
  if (g < N) excl[g] = s[t] - v;
  if (t == 511) bsums[blockIdx.x] = s[511];
}

__global__ void k_scan2(int* __restrict__ bsums, int nb) {
  __shared__ int s[128];
  int t = threadIdx.x;
  int v = (t < nb) ? bsums[t] : 0;
  s[t] = v;
  __syncthreads();
  for (int off = 1; off < 128; off <<= 1) {
    int add = (t >= off) ? s[t - off] : 0;
    __syncthreads();
    s[t] += add;
    __syncthreads();
  }
  if (t < nb) bsums[t] = s[t] - v;
}

__global__ void k_scan3(int* __restrict__ row_off, const int* __restrict__ bsums,
                        int N, int E) {
  int g = blockIdx.x * blockDim.x + threadIdx.x;
  if (g < N) row_off[g] += bsums[g >> 9];
  if (g == 0) row_off[N] = E;
}

__global__ void k_fill(const int* __restrict__ src, const int* __restrict__ dst,
                       const int* __restrict__ row_off, int* __restrict__ cursor,
                       int* __restrict__ ssrc, int E) {
  int e = blockIdx.x * blockDim.x + threadIdx.x;
  if (e < E) {
    int d = dst[e];
    int pos = atomicAdd(&cursor[d], 1);
    ssrc[row_off[d] + pos] = src[e];
  }
}

// ---------------- fp32 GEMM: 128x128 tile, 8x8 micro, dbuf LDS ----------------
// C = (A * rowscale[:,None]) @ B.  A: MxK rm, B: KxN rm. K%16==0, N%128==0.
__launch_bounds__(256)
__global__ void k_gemm128(const float* __restrict__ A, const float* __restrict__ B,
                          const float* __restrict__ rowscale, float* __restrict__ C,
                          int M, int N, int K) {
  __shared__ float As[2][16][132];   // k-major; stride 132 -> 2-way-only conflicts
  __shared__ float Bs[2][16 * 128];  // linear (global_load_lds dest)

  const int tid  = threadIdx.x;
  const int wid  = tid >> 6;
  const int lane = tid & 63;
  const int bm = blockIdx.x * 128;
  const int bn = blockIdx.y * 128;
  const int tRow = (wid >> 1) * 64 + 8 * (lane >> 3);
  const int tCol = (wid & 1) * 64 + 8 * (lane & 7);

  // A staging assignment: f in {tid, tid+256}; m=f>>2 (0..127), kq=f&3 (k-quads)
  const int m0 = tid >> 2, kq = tid & 3;
  const int m1 = m0 + 64;
  const int gm0 = bm + m0, gm1 = bm + m1;
  const bool v0ok = gm0 < M, v1ok = gm1 < M;
  const float sc0 = v0ok ? rowscale[gm0] : 0.f;
  const float sc1 = v1ok ? rowscale[gm1] : 0.f;
  const float* arow0 = A + (size_t)(v0ok ? gm0 : 0) * K + kq * 4;
  const float* arow1 = A + (size_t)(v1ok ? gm1 : 0) * K + kq * 4;

  float4 av0, av1;
  auto loadA = [&](int k0) {
    av0 = v0ok ? *(const float4*)(arow0 + k0) : make_float4(0, 0, 0, 0);
    av1 = v1ok ? *(const float4*)(arow1 + k0) : make_float4(0, 0, 0, 0);
  };
  auto writeA = [&](int buf) {
    As[buf][kq * 4 + 0][m0] = av0.x * sc0;
    As[buf][kq * 4 + 1][m0] = av0.y * sc0;
    As[buf][kq * 4 + 2][m0] = av0.z * sc0;
    As[buf][kq * 4 + 3][m0] = av0.w * sc0;
    As[buf][kq * 4 + 0][m1] = av1.x * sc1;
    As[buf][kq * 4 + 1][m1] = av1.y * sc1;
    As[buf][kq * 4 + 2][m1] = av1.z * sc1;
    As[buf][kq * 4 + 3][m1] = av1.w * sc1;
  };
  auto stageB = [&](int buf, int k0) {
#pragma unroll
    for (int i = 0; i < 2; ++i) {
      const int inst = wid * 2 + i;            // 0..7, wave-uniform
      const int f = inst * 256 + lane * 4;     // float index in 16x128 tile
      const int kk = f >> 7, col = f & 127;
      const float* g = B + (size_t)(k0 + kk) * N + bn + col;
      __builtin_amdgcn_global_load_lds(
          (const __attribute__((address_space(1))) unsigned int*)g,
          (__attribute__((address_space(3))) unsigned int*)&Bs[buf][inst * 256],
          16, 0, 0);
    }
  };

  float acc[8][8] = {};
  const int nt = K >> 4;

  loadA(0);
  stageB(0, 0);
  asm volatile("s_waitcnt vmcnt(0)" ::: "memory");
  writeA(0);
  __syncthreads();

  for (int t = 0; t < nt; ++t) {
    const int cur = t & 1;
    const bool more = (t + 1 < nt);
    if (more) { loadA((t + 1) << 4); stageB(cur ^ 1, (t + 1) << 4); }

#pragma unroll
    for (int kk = 0; kk < 16; ++kk) {
      const float* ap = &As[cur][kk][tRow];
      const float* bp = &Bs[cur][kk * 128 + tCol];
      float4 A0 = *(const float4*)ap;
      float4 A1 = *(const float4*)(ap + 4);
      float4 B0 = *(const float4*)bp;
      float4 B1 = *(const float4*)(bp + 4);
      float a[8] = {A0.x, A0.y, A0.z, A0.w, A1.x, A1.y, A1.z, A1.w};
      float b[8] = {B0.x, B0.y, B0.z, B0.w, B1.x, B1.y, B1.z, B1.w};
#pragma unroll
      for (int i = 0; i < 8; ++i)
#pragma unroll
        for (int j = 0; j < 8; ++j)
          acc[i][j] = fmaf(a[i], b[j], acc[i][j]);
    }

    if (more) {
      asm volatile("s_waitcnt vmcnt(0)" ::: "memory");
      writeA(cur ^ 1);
    }
    __syncthreads();
  }

#pragma unroll
  for (int i = 0; i < 8; ++i) {
    int gm = bm + tRow + i;
    if (gm < M) {
      float* cp = C + (size_t)gm * N + bn + tCol;
      *(float4*)cp       = make_float4(acc[i][0], acc[i][1], acc[i][2], acc[i][3]);
      *(float4*)(cp + 4) = make_float4(acc[i][4], acc[i][5], acc[i][6], acc[i][7]);
    }
  }
}

// ---------------- CSR aggregation (one wave per dst node, 4-deep MLP) ----------------
template <int F, bool RELU>
__launch_bounds__(256)
__global__ void k_agg(const float* __restrict__ Hpre, const int* __restrict__ row_off,
                      const int* __restrict__ ssrc, const float* __restrict__ norm_dst,
                      const float* __restrict__ bias, float* __restrict__ out, int N) {
  int wid = (blockIdx.x * 256 + threadIdx.x) >> 6;
  int lane = threadIdx.x & 63;
  if (wid >= N) return;
  int beg = row_off[wid], end = row_off[wid + 1];

  if constexpr (F == 256) {
    float4 a0 = make_float4(0, 0, 0, 0), a1 = a0, a2 = a0, a3 = a0;
    int e = beg;
    for (; e + 4 <= end; e += 4) {
      int s0 = ssrc[e], s1 = ssrc[e + 1], s2 = ssrc[e + 2], s3 = ssrc[e + 3];
      float4 v0 = *(const float4*)(Hpre + (size_t)s0 * 256 + lane * 4);
      float4 v1 = *(const float4*)(Hpre + (size_t)s1 * 256 + lane * 4);
      float4 v2 = *(const float4*)(Hpre + (size_t)s2 * 256 + lane * 4);
      float4 v3 = *(const float4*)(Hpre + (size_t)s3 * 256 + lane * 4);
      a0.x += v0.x; a0.y += v0.y; a0.z += v0.z; a0.w += v0.w;
      a1.x += v1.x; a1.y += v1.y; a1.z += v1.z; a1.w += v1.w;
      a2.x += v2.x; a2.y += v2.y; a2.z += v2.z; a2.w += v2.w;
      a3.x += v3.x; a3.y += v3.y; a3.z += v3.z; a3.w += v3.w;
    }
    for (; e < end; ++e) {
      int s = ssrc[e];
      float4 v = *(const float4*)(Hpre + (size_t)s * 256 + lane * 4);
      a0.x += v.x; a0.y += v.y; a0.z += v.z; a0.w += v.w;
    }
    float4 acc = make_float4(a0.x + a1.x + a2.x + a3.x, a0.y + a1.y + a2.y + a3.y,
                             a0.z + a1.z + a2.z + a3.z, a0.w + a1.w + a2.w + a3.w);
    float nd = norm_dst[wid];
    const float4 bb = *(const float4*)(bias + lane * 4);
    float4 o = make_float4(fmaf(acc.x, nd, bb.x), fmaf(acc.y, nd, bb.y),
                           fmaf(acc.z, nd, bb.z), fmaf(acc.w, nd, bb.w));
    if (RELU) {
      o.x = fmaxf(o.x, 0.f); o.y = fmaxf(o.y, 0.f);
      o.z = fmaxf(o.z, 0.f); o.w = fmaxf(o.w, 0.f);
    }
    *(float4*)(out + (size_t)wid * 256 + lane * 4) = o;
  } else {
    float2 a0 = make_float2(0, 0), a1 = a0, a2 = a0, a3 = a0;
    int e = beg;
    for (; e + 4 <= end; e += 4) {
      int s0 = ssrc[e], s1 = ssrc[e + 1], s2 = ssrc[e + 2], s3 = ssrc[e + 3];
      float2 v0 = *(const float2*)(Hpre + (size_t)s0 * 128 + lane * 2);
      float2 v1 = *(const float2*)(Hpre + (size_t)s1 * 128 + lane * 2);
      float2 v2 = *(const float2*)(Hpre + (size_t)s2 * 128 + lane * 2);
      float2 v3 = *(const float2*)(Hpre + (size_t)s3 * 128 + lane * 2);
      a0.x += v0.x; a0.y += v0.y;
      a1.x += v1.x; a1.y += v1.y;
      a2.x += v2.x; a2.y += v2.y;
      a3.x += v3.x; a3.y += v3.y;
    }
    for (; e < end; ++e) {
      int s = ssrc[e];
      float2 v = *(const float2*)(Hpre + (size_t)s * 128 + lane * 2);
      a0.x += v.x; a0.y += v.y;
    }
    float2 acc = make_float2(a0.x + a1.x + a2.x + a3.x, a0.y + a1.y + a2.y + a3.y);
    float nd = norm_dst[wid];
    const float2 bb = *(const float2*)(bias + lane * 2);
    float2 o = make_float2(fmaf(acc.x, nd, bb.x), fmaf(acc.y, nd, bb.y));
    if (RELU) { o.x = fmaxf(o.x, 0.f); o.y = fmaxf(o.y, 0.f); }
    *(float2*)(out + (size_t)wid * 128 + lane * 2) = o;
  }
}

// ---------------- launch ----------------

extern "C" void kernel_launch(void* const* d_in, const int* in_sizes, int n_in,
                              void* d_out, int out_size, void* d_ws, size_t ws_size,
                              hipStream_t stream) {
  const float* X  = (const float*)d_in[0];
  const float* W1 = (const float*)d_in[1];
  const float* b1 = (const float*)d_in[2];
  const float* W2 = (const float*)d_in[3];
  const float* b2 = (const float*)d_in[4];
  const int* src  = (const int*)d_in[5];
  const int* dst  = (const int*)d_in[6];
  float* out = (float*)d_out;

  char* p = (char*)d_ws;
  auto alloc = [&](size_t bytes) -> char* {
    char* r = p;
    p += (bytes + 255) & ~(size_t)255;
    return r;
  };
  float* H1pre  = (float*)alloc((size_t)NN * HID * 4);
  float* H1post = (float*)alloc((size_t)NN * HID * 4);
  float* H2pre  = H1pre;  // reuse
  int* deg_out  = (int*)alloc((size_t)NN * 4);
  int* deg_in   = (int*)alloc((size_t)NN * 4);
  int* cursor   = (int*)alloc((size_t)NN * 4);
  int* row_off  = (int*)alloc((size_t)(NN + 1) * 4);
  int* bsums    = (int*)alloc(512);
  float* nsrc   = (float*)alloc((size_t)NN * 4);
  float* ndst   = (float*)alloc((size_t)NN * 4);
  int* ssrc     = (int*)alloc((size_t)NE * 4);

  hipMemsetAsync(deg_out, 0, (size_t)((char*)row_off - (char*)deg_out), stream);

  k_degree<<<(NE + 255) / 256, 256, 0, stream>>>(src, dst, deg_out, deg_in, NE);
  k_norm<<<(NN + 255) / 256, 256, 0, stream>>>(deg_out, deg_in, nsrc, ndst, NN);

  int nb = (NN + 511) / 512;
  k_scan1<<<nb, 512, 0, stream>>>(deg_in, row_off, bsums, NN);
  k_scan2<<<1, 128, 0, stream>>>(bsums, nb);
  k_scan3<<<(NN + 255) / 256, 256, 0, stream>>>(row_off, bsums, NN, NE);
  k_fill<<<(NE + 255) / 256, 256, 0, stream>>>(src, dst, row_off, cursor, ssrc, NE);

  dim3 g1((NN + 127) / 128, HID / 128);
  k_gemm128<<<g1, 256, 0, stream>>>(X, W1, nsrc, H1pre, NN, HID, IN_F);
  k_agg<256, true><<<(NN * 64 + 255) / 256, 256, 0, stream>>>(
      H1pre, row_off, ssrc, ndst, b1, H1post, NN);

  dim3 g2((NN + 127) / 128, OUTF / 128);
  k_gemm128<<<g2, 256, 0, stream>>>(H1post, W2, nsrc, H2pre, NN, OUTF, HID);
  k_agg<128, false><<<(NN * 64 + 255) / 256, 256, 0, stream>>>(
      H2pre, row_off, ssrc, ndst, b2, out, NN);
}

// Round 3
// 521.267 us; speedup vs baseline: 1.5546x; 1.5546x over previous
//
#include <hip/hip_runtime.h>
#include <cstdint>
#include <cstddef>

#define NN 50000
#define NE 800000
static constexpr int IN_F = 512;
static constexpr int HID  = 256;
static constexpr int OUTF = 128;

typedef __attribute__((ext_vector_type(8))) short short8;
typedef __attribute__((ext_vector_type(4))) float f32x4;

__device__ __forceinline__ unsigned rne_bf16(float f) {
  unsigned b = __float_as_uint(f);
  return (b + 0x7FFFu + ((b >> 16) & 1u)) >> 16;
}

// ---------------- graph preprocessing ----------------

__global__ void k_degree(const int* __restrict__ src, const int* __restrict__ dst,
                         int* __restrict__ deg_out, int* __restrict__ deg_in, int E) {
  int e = blockIdx.x * blockDim.x + threadIdx.x;
  if (e < E) {
    atomicAdd(&deg_out[src[e]], 1);
    atomicAdd(&deg_in[dst[e]], 1);
  }
}

__global__ void k_norm(const int* __restrict__ deg_out, const int* __restrict__ deg_in,
                       float* __restrict__ norm_src, float* __restrict__ norm_dst, int N) {
  int i = blockIdx.x * blockDim.x + threadIdx.x;
  if (i < N) {
    int dO = deg_out[i]; if (dO < 1) dO = 1;
    int dI = deg_in[i];  if (dI < 1) dI = 1;
    norm_src[i] = rsqrtf((float)dO);
    norm_dst[i] = rsqrtf((float)dI);
  }
}

__global__ void k_scan1(const int* __restrict__ deg_in, int* __restrict__ excl,
                        int* __restrict__ bsums, int N) {
  __shared__ int s[512];
  int t = threadIdx.x;
  int g = blockIdx.x * 512 + t;
  int v = (g < N) ? deg_in[g] : 0;
  s[t] = v;
  __syncthreads();
  for (int off = 1; off < 512; off <<= 1) {
    int add = (t >= off) ? s[t - off] : 0;
    __syncthreads();
    s[t] += add;
    __syncthreads();
  }
  if (g < N) excl[g] = s[t] - v;
  if (t == 511) bsums[blockIdx.x] = s[511];
}

__global__ void k_scan2(int* __restrict__ bsums, int nb) {
  __shared__ int s[128];
  int t = threadIdx.x;
  int v = (t < nb) ? bsums[t] : 0;
  s[t] = v;
  __syncthreads();
  for (int off = 1; off < 128; off <<= 1) {
    int add = (t >= off) ? s[t - off] : 0;
    __syncthreads();
    s[t] += add;
    __syncthreads();
  }
  if (t < nb) bsums[t] = s[t] - v;
}

__global__ void k_scan3(int* __restrict__ row_off, const int* __restrict__ bsums,
                        int N, int E) {
  int g = blockIdx.x * blockDim.x + threadIdx.x;
  if (g < N) row_off[g] += bsums[g >> 9];
  if (g == 0) row_off[N] = E;
}

__global__ void k_fill(const int* __restrict__ src, const int* __restrict__ dst,
                       const int* __restrict__ row_off, int* __restrict__ cursor,
                       int* __restrict__ ssrc, int E) {
  int e = blockIdx.x * blockDim.x + threadIdx.x;
  if (e < E) {
    int d = dst[e];
    int pos = atomicAdd(&cursor[d], 1);
    ssrc[row_off[d] + pos] = src[e];
  }
}

// ---------------- weight split+transpose: W[K][N] -> hiT/loT[N][K] bf16 ----------------
__global__ void k_convW(const float* __restrict__ W, unsigned short* __restrict__ hiT,
                        unsigned short* __restrict__ loT, int K, int N) {
  int t = blockIdx.x * blockDim.x + threadIdx.x;
  if (t >= K * N) return;
  int n = t / K, k = t - n * K;
  float f = W[(size_t)k * N + n];
  unsigned b = __float_as_uint(f);
  unsigned hi = b >> 16;                       // truncated hi
  float hif = __uint_as_float(b & 0xFFFF0000u);
  unsigned lo = rne_bf16(f - hif);             // exact remainder, RNE to bf16
  hiT[t] = (unsigned short)hi;
  loT[t] = (unsigned short)lo;
}

// ---------------- split-bf16 MFMA GEMM ----------------
// C[M][N] = (A * rowscale?) @ B, via Ahi*Bhi + Ahi*Blo + Alo*Bhi.
// A fp32 MxK row-major (split on the fly). B pre-split as BhiT/BloT [N][K] bf16.
// 128x128 tile, BK=32, 256 thr (4 waves, 2x2), fragment-major LDS (conflict-free).
template <bool SCALE>
__launch_bounds__(256)
__global__ void k_gemm_mfma(const float* __restrict__ A,
                            const unsigned short* __restrict__ BhiT,
                            const unsigned short* __restrict__ BloT,
                            const float* __restrict__ rowscale,
                            float* __restrict__ C, int M, int N, int K) {
  __shared__ uint4 sAhi[2][512];  // 8 frags x 64 lane-chunks x 16B = 8KB/buf
  __shared__ uint4 sAlo[2][512];
  __shared__ uint4 sBhi[2][512];
  __shared__ uint4 sBlo[2][512];

  const int tid = threadIdx.x;
  const int wid = tid >> 6, lane = tid & 63;
  const int bm = blockIdx.x * 128, bn = blockIdx.y * 128;
  const int wrow = wid >> 1, wcol = wid & 1;

  // A staging: thread owns chunks c0=tid, c1=256+tid. frag=c>>6, role=c&63.
  // role r of frag f holds A[bm+f*16+(r&15)][k0+(r>>4)*8 .. +8] as 8 bf16.
  const int c0 = tid, c1 = 256 + tid;
  const int f0 = c0 >> 6, r0 = c0 & 63;
  const int f1 = c1 >> 6, r1 = c1 & 63;
  int g0 = bm + f0 * 16 + (r0 & 15); if (g0 > M - 1) g0 = M - 1;
  int g1 = bm + f1 * 16 + (r1 & 15); if (g1 > M - 1) g1 = M - 1;
  const float sc0 = SCALE ? rowscale[g0] : 1.0f;
  const float sc1 = SCALE ? rowscale[g1] : 1.0f;
  const float* pa0 = A + (size_t)g0 * K + (r0 >> 4) * 8;
  const float* pa1 = A + (size_t)g1 * K + (r1 >> 4) * 8;

  float4 av[4];
  auto loadA = [&](int k0) {
    av[0] = *(const float4*)(pa0 + k0);
    av[1] = *(const float4*)(pa0 + k0 + 4);
    av[2] = *(const float4*)(pa1 + k0);
    av[3] = *(const float4*)(pa1 + k0 + 4);
  };
  auto cvtWriteA = [&](int buf) {
#pragma unroll
    for (int j = 0; j < 2; ++j) {
      const float s = j ? sc1 : sc0;
      const float4 u = av[j * 2], v = av[j * 2 + 1];
      float fv[8] = {u.x, u.y, u.z, u.w, v.x, v.y, v.z, v.w};
      unsigned hb[8], lb[8];
#pragma unroll
      for (int i = 0; i < 8; ++i) {
        float f = SCALE ? fv[i] * s : fv[i];
        unsigned b = __float_as_uint(f);
        hb[i] = b >> 16;
        float hif = __uint_as_float(b & 0xFFFF0000u);
        lb[i] = rne_bf16(f - hif);
      }
      uint4 H = make_uint4(hb[0] | (hb[1] << 16), hb[2] | (hb[3] << 16),
                           hb[4] | (hb[5] << 16), hb[6] | (hb[7] << 16));
      uint4 L = make_uint4(lb[0] | (lb[1] << 16), lb[2] | (lb[3] << 16),
                           lb[4] | (lb[5] << 16), lb[6] | (lb[7] << 16));
      const int c = j ? c1 : c0;
      sAhi[buf][c] = H;   // linear b128 writes: conflict-free
      sAlo[buf][c] = L;
    }
  };
  // B staging: 16 global_load_lds (1KB each), 4 per wave; per-lane global src
  // is the fragment gather, LDS dest linear.
  auto stageB = [&](int buf, int k0) {
#pragma unroll
    for (int i = 0; i < 4; ++i) {
      const int j = wid * 4 + i;  // wave-uniform 0..15
      const int frag = j & 7;
      const unsigned short* WT = (j < 8) ? BhiT : BloT;
      const unsigned short* g =
          WT + (size_t)(bn + frag * 16 + (lane & 15)) * K + k0 + (lane >> 4) * 8;
      uint4* dst = (j < 8) ? &sBhi[buf][frag * 64] : &sBlo[buf][frag * 64];
      __builtin_amdgcn_global_load_lds(
          (const __attribute__((address_space(1))) unsigned int*)g,
          (__attribute__((address_space(3))) unsigned int*)dst, 16, 0, 0);
    }
  };

  f32x4 acc[4][4] = {};
  auto mfmaPhase = [&](int buf) {
    short8 ah[4], bh[4], tt[4];
#pragma unroll
    for (int m = 0; m < 4; ++m)
      ah[m] = *(const short8*)&sAhi[buf][(wrow * 4 + m) * 64 + lane];
#pragma unroll
    for (int n = 0; n < 4; ++n)
      bh[n] = *(const short8*)&sBhi[buf][(wcol * 4 + n) * 64 + lane];
#pragma unroll
    for (int m = 0; m < 4; ++m)
#pragma unroll
      for (int n = 0; n < 4; ++n)
        acc[m][n] = __builtin_amdgcn_mfma_f32_16x16x32_bf16(ah[m], bh[n], acc[m][n], 0, 0, 0);
#pragma unroll
    for (int n = 0; n < 4; ++n)
      tt[n] = *(const short8*)&sBlo[buf][(wcol * 4 + n) * 64 + lane];
#pragma unroll
    for (int m = 0; m < 4; ++m)
#pragma unroll
      for (int n = 0; n < 4; ++n)
        acc[m][n] = __builtin_amdgcn_mfma_f32_16x16x32_bf16(ah[m], tt[n], acc[m][n], 0, 0, 0);
#pragma unroll
    for (int m = 0; m < 4; ++m)
      tt[m] = *(const short8*)&sAlo[buf][(wrow * 4 + m) * 64 + lane];
#pragma unroll
    for (int m = 0; m < 4; ++m)
#pragma unroll
      for (int n = 0; n < 4; ++n)
        acc[m][n] = __builtin_amdgcn_mfma_f32_16x16x32_bf16(tt[m], bh[n], acc[m][n], 0, 0, 0);
  };

  const int nt = K >> 5;
  loadA(0);
  stageB(0, 0);
  cvtWriteA(0);
  __syncthreads();
  for (int t = 0; t < nt; ++t) {
    const int cur = t & 1;
    const bool more = (t + 1 < nt);
    if (more) { loadA((t + 1) << 5); stageB(cur ^ 1, (t + 1) << 5); }  // issue early
    mfmaPhase(cur);
    if (more) cvtWriteA(cur ^ 1);  // write late (T14)
    __syncthreads();
  }

  // epilogue: C/D frag mapping col=lane&15, row=(lane>>4)*4+reg
#pragma unroll
  for (int m = 0; m < 4; ++m) {
    const int rb = bm + wrow * 64 + m * 16 + (lane >> 4) * 4;
#pragma unroll
    for (int r = 0; r < 4; ++r) {
      const int gm = rb + r;
      if (gm < M) {
        float* cp = C + (size_t)gm * N + bn + wcol * 64 + (lane & 15);
#pragma unroll
        for (int n = 0; n < 4; ++n) cp[n * 16] = acc[m][n][r];
      }
    }
  }
}

// ---------------- CSR aggregation (one wave per dst node) ----------------
template <int F, bool RELU, bool OSCALE>
__launch_bounds__(256)
__global__ void k_agg(const float* __restrict__ Hpre, const int* __restrict__ row_off,
                      const int* __restrict__ ssrc, const float* __restrict__ norm_dst,
                      const float* __restrict__ bias, const float* __restrict__ oscale,
                      float* __restrict__ out, int N) {
  int wid = (blockIdx.x * 256 + threadIdx.x) >> 6;
  int lane = threadIdx.x & 63;
  if (wid >= N) return;
  int beg = row_off[wid], end = row_off[wid + 1];

  if constexpr (F == 256) {
    float4 a0 = make_float4(0, 0, 0, 0), a1 = a0, a2 = a0, a3 = a0;
    int e = beg;
    for (; e + 4 <= end; e += 4) {
      int s0 = ssrc[e], s1 = ssrc[e + 1], s2 = ssrc[e + 2], s3 = ssrc[e + 3];
      float4 v0 = *(const float4*)(Hpre + (size_t)s0 * 256 + lane * 4);
      float4 v1 = *(const float4*)(Hpre + (size_t)s1 * 256 + lane * 4);
      float4 v2 = *(const float4*)(Hpre + (size_t)s2 * 256 + lane * 4);
      float4 v3 = *(const float4*)(Hpre + (size_t)s3 * 256 + lane * 4);
      a0.x += v0.x; a0.y += v0.y; a0.z += v0.z; a0.w += v0.w;
      a1.x += v1.x; a1.y += v1.y; a1.z += v1.z; a1.w += v1.w;
      a2.x += v2.x; a2.y += v2.y; a2.z += v2.z; a2.w += v2.w;
      a3.x += v3.x; a3.y += v3.y; a3.z += v3.z; a3.w += v3.w;
    }
    for (; e < end; ++e) {
      int s = ssrc[e];
      float4 v = *(const float4*)(Hpre + (size_t)s * 256 + lane * 4);
      a0.x += v.x; a0.y += v.y; a0.z += v.z; a0.w += v.w;
    }
    float4 acc = make_float4(a0.x + a1.x + a2.x + a3.x, a0.y + a1.y + a2.y + a3.y,
                             a0.z + a1.z + a2.z + a3.z, a0.w + a1.w + a2.w + a3.w);
    float nd = norm_dst[wid];
    const float4 bb = *(const float4*)(bias + lane * 4);
    float4 o = make_float4(fmaf(acc.x, nd, bb.x), fmaf(acc.y, nd, bb.y),
                           fmaf(acc.z, nd, bb.z), fmaf(acc.w, nd, bb.w));
    if (RELU) {
      o.x = fmaxf(o.x, 0.f); o.y = fmaxf(o.y, 0.f);
      o.z = fmaxf(o.z, 0.f); o.w = fmaxf(o.w, 0.f);
    }
    if (OSCALE) {
      float os = oscale[wid];
      o.x *= os; o.y *= os; o.z *= os; o.w *= os;
    }
    *(float4*)(out + (size_t)wid * 256 + lane * 4) = o;
  } else {
    float2 a0 = make_float2(0, 0), a1 = a0, a2 = a0, a3 = a0;
    int e = beg;
    for (; e + 4 <= end; e += 4) {
      int s0 = ssrc[e], s1 = ssrc[e + 1], s2 = ssrc[e + 2], s3 = ssrc[e + 3];
      float2 v0 = *(const float2*)(Hpre + (size_t)s0 * 128 + lane * 2);
      float2 v1 = *(const float2*)(Hpre + (size_t)s1 * 128 + lane * 2);
      float2 v2 = *(const float2*)(Hpre + (size_t)s2 * 128 + lane * 2);
      float2 v3 = *(const float2*)(Hpre + (size_t)s3 * 128 + lane * 2);
      a0.x += v0.x; a0.y += v0.y;
      a1.x += v1.x; a1.y += v1.y;
      a2.x += v2.x; a2.y += v2.y;
      a3.x += v3.x; a3.y += v3.y;
    }
    for (; e < end; ++e) {
      int s = ssrc[e];
      float2 v = *(const float2*)(Hpre + (size_t)s * 128 + lane * 2);
      a0.x += v.x; a0.y += v.y;
    }
    float2 acc = make_float2(a0.x + a1.x + a2.x + a3.x, a0.y + a1.y + a2.y + a3.y);
    float nd = norm_dst[wid];
    const float2 bb = *(const float2*)(bias + lane * 2);
    float2 o = make_float2(fmaf(acc.x, nd, bb.x), fmaf(acc.y, nd, bb.y));
    if (RELU) { o.x = fmaxf(o.x, 0.f); o.y = fmaxf(o.y, 0.f); }
    if (OSCALE) {
      float os = oscale[wid];
      o.x *= os; o.y *= os;
    }
    *(float2*)(out + (size_t)wid * 128 + lane * 2) = o;
  }
}

// ---------------- launch ----------------

extern "C" void kernel_launch(void* const* d_in, const int* in_sizes, int n_in,
                              void* d_out, int out_size, void* d_ws, size_t ws_size,
                              hipStream_t stream) {
  const float* X  = (const float*)d_in[0];
  const float* W1 = (const float*)d_in[1];
  const float* b1 = (const float*)d_in[2];
  const float* W2 = (const float*)d_in[3];
  const float* b2 = (const float*)d_in[4];
  const int* src  = (const int*)d_in[5];
  const int* dst  = (const int*)d_in[6];
  float* out = (float*)d_out;

  char* p = (char*)d_ws;
  auto alloc = [&](size_t bytes) -> char* {
    char* r = p;
    p += (bytes + 255) & ~(size_t)255;
    return r;
  };
  float* H1pre  = (float*)alloc((size_t)NN * HID * 4);  // layer-1 pre-agg (fp32)
  float* H1post = (float*)alloc((size_t)NN * HID * 4);  // relu(...)*nsrc (fp32)
  float* H2pre  = H1pre;                                // reuse
  unsigned short* W1hiT = (unsigned short*)alloc((size_t)HID * IN_F * 2);
  unsigned short* W1loT = (unsigned short*)alloc((size_t)HID * IN_F * 2);
  unsigned short* W2hiT = (unsigned short*)alloc((size_t)OUTF * HID * 2);
  unsigned short* W2loT = (unsigned short*)alloc((size_t)OUTF * HID * 2);
  int* deg_out  = (int*)alloc((size_t)NN * 4);
  int* deg_in   = (int*)alloc((size_t)NN * 4);
  int* cursor   = (int*)alloc((size_t)NN * 4);
  int* row_off  = (int*)alloc((size_t)(NN + 1) * 4);
  int* bsums    = (int*)alloc(512);
  float* nsrc   = (float*)alloc((size_t)NN * 4);
  float* ndst   = (float*)alloc((size_t)NN * 4);
  int* ssrc     = (int*)alloc((size_t)NE * 4);

  hipMemsetAsync(deg_out, 0, (size_t)((char*)row_off - (char*)deg_out), stream);

  k_degree<<<(NE + 255) / 256, 256, 0, stream>>>(src, dst, deg_out, deg_in, NE);
  k_norm<<<(NN + 255) / 256, 256, 0, stream>>>(deg_out, deg_in, nsrc, ndst, NN);

  int nb = (NN + 511) / 512;
  k_scan1<<<nb, 512, 0, stream>>>(deg_in, row_off, bsums, NN);
  k_scan2<<<1, 128, 0, stream>>>(bsums, nb);
  k_scan3<<<(NN + 255) / 256, 256, 0, stream>>>(row_off, bsums, NN, NE);
  k_fill<<<(NE + 255) / 256, 256, 0, stream>>>(src, dst, row_off, cursor, ssrc, NE);

  k_convW<<<(IN_F * HID + 255) / 256, 256, 0, stream>>>(W1, W1hiT, W1loT, IN_F, HID);
  k_convW<<<(HID * OUTF + 255) / 256, 256, 0, stream>>>(W2, W2hiT, W2loT, HID, OUTF);

  // layer 1
  dim3 g1((NN + 127) / 128, HID / 128);
  k_gemm_mfma<true><<<g1, 256, 0, stream>>>(X, W1hiT, W1loT, nsrc, H1pre, NN, HID, IN_F);
  k_agg<256, true, true><<<(NN * 64 + 255) / 256, 256, 0, stream>>>(
      H1pre, row_off, ssrc, ndst, b1, nsrc, H1post, NN);

  // layer 2
  dim3 g2((NN + 127) / 128, OUTF / 128);
  k_gemm_mfma<false><<<g2, 256, 0, stream>>>(H1post, W2hiT, W2loT, nullptr, H2pre, NN, OUTF, HID);
  k_agg<128, false, false><<<(NN * 64 + 255) / 256, 256, 0, stream>>>(
      H2pre, row_off, ssrc, ndst, b2, nullptr, out, NN);
}

// Round 5
// 423.051 us; speedup vs baseline: 1.9155x; 1.2322x over previous
//
#include <hip/hip_runtime.h>
#include <cstdint>
#include <cstddef>

#define NN 50000
#define NE 800000
static constexpr int IN_F = 512;
static constexpr int HID  = 256;
static constexpr int OUTF = 128;

typedef __attribute__((ext_vector_type(8))) _Float16 half8;
typedef __attribute__((ext_vector_type(4))) _Float16 half4v;
typedef __attribute__((ext_vector_type(2))) _Float16 half2v;
typedef __attribute__((ext_vector_type(4))) float f32x4;

// ---------------- graph preprocessing ----------------

__global__ void k_degree(const int* __restrict__ src, const int* __restrict__ dst,
                         int* __restrict__ deg_out, int* __restrict__ deg_in, int E) {
  int e = blockIdx.x * blockDim.x + threadIdx.x;
  if (e < E) {
    atomicAdd(&deg_out[src[e]], 1);
    atomicAdd(&deg_in[dst[e]], 1);
  }
}

__global__ void k_norm(const int* __restrict__ deg_out, const int* __restrict__ deg_in,
                       float* __restrict__ norm_src, float* __restrict__ norm_dst, int N) {
  int i = blockIdx.x * blockDim.x + threadIdx.x;
  if (i < N) {
    int dO = deg_out[i]; if (dO < 1) dO = 1;
    int dI = deg_in[i];  if (dI < 1) dI = 1;
    norm_src[i] = rsqrtf((float)dO);
    norm_dst[i] = rsqrtf((float)dI);
  }
}

__global__ void k_scan1(const int* __restrict__ deg_in, int* __restrict__ excl,
                        int* __restrict__ bsums, int N) {
  __shared__ int s[512];
  int t = threadIdx.x;
  int g = blockIdx.x * 512 + t;
  int v = (g < N) ? deg_in[g] : 0;
  s[t] = v;
  __syncthreads();
  for (int off = 1; off < 512; off <<= 1) {
    int add = (t >= off) ? s[t - off] : 0;
    __syncthreads();
    s[t] += add;
    __syncthreads();
  }
  if (g < N) excl[g] = s[t] - v;
  if (t == 511) bsums[blockIdx.x] = s[511];
}

__global__ void k_scan2(int* __restrict__ bsums, int nb) {
  __shared__ int s[128];
  int t = threadIdx.x;
  int v = (t < nb) ? bsums[t] : 0;
  s[t] = v;
  __syncthreads();
  for (int off = 1; off < 128; off <<= 1) {
    int add = (t >= off) ? s[t - off] : 0;
    __syncthreads();
    s[t] += add;
    __syncthreads();
  }
  if (t < nb) bsums[t] = s[t] - v;
}

__global__ void k_scan3(int* __restrict__ row_off, const int* __restrict__ bsums,
                        int N, int E) {
  int g = blockIdx.x * blockDim.x + threadIdx.x;
  if (g < N) row_off[g] += bsums[g >> 9];
  if (g == 0) row_off[N] = E;
}

__global__ void k_fill(const int* __restrict__ src, const int* __restrict__ dst,
                       const int* __restrict__ row_off, int* __restrict__ cursor,
                       int* __restrict__ ssrc, int E) {
  int e = blockIdx.x * blockDim.x + threadIdx.x;
  if (e < E) {
    int d = dst[e];
    int pos = atomicAdd(&cursor[d], 1);
    ssrc[row_off[d] + pos] = src[e];
  }
}

// ---------------- weight transpose+cvt: W[K][N] fp32 -> WT[N][K] fp16 ----------------
__global__ void k_convW(const float* __restrict__ W, _Float16* __restrict__ WT,
                        int K, int N) {
  int t = blockIdx.x * blockDim.x + threadIdx.x;
  if (t >= K * N) return;
  int n = t / K, k = t - n * K;
  WT[t] = (_Float16)W[(size_t)k * N + n];
}

// ---------------- fp16 MFMA GEMM ----------------
// C[M][N](fp16) = (A * rowscale?) @ B.  B pre-cvt as BT[N][K] fp16.
// A: fp32 (AF32: cvt-in-staging) or fp16 (direct global_load_lds).
// 128x128 tile, BK=32, 4 waves 2x2, fragment-major LDS (conflict-free).
template <bool AF32, bool SCALE>
__launch_bounds__(256)
__global__ void k_gemm_f16(const void* __restrict__ Ap,
                           const _Float16* __restrict__ BT,
                           const float* __restrict__ rowscale,
                           _Float16* __restrict__ C, int M, int N, int K) {
  __shared__ uint4 sA[2][512];  // 8 frags x 64 chunks x 16B = 8KB/buf
  __shared__ uint4 sB[2][512];

  const int tid = threadIdx.x;
  const int wid = tid >> 6, lane = tid & 63;
  const int bm = blockIdx.x * 128, bn = blockIdx.y * 128;
  const int wrow = wid >> 1, wcol = wid & 1;

  const _Float16* Af16 = (const _Float16*)Ap;
  const float* Af32 = (const float*)Ap;

  // fp32 A staging: thread owns chunks c0=tid, c1=256+tid. frag=c>>6, role=c&63.
  // role r of frag f holds A[bm+f*16+(r&15)][k0+(r>>4)*8 .. +8] as 8 fp16.
  const int c0 = tid, c1 = 256 + tid;
  const float *pa0 = nullptr, *pa1 = nullptr;
  float sc0 = 1.f, sc1 = 1.f;
  if constexpr (AF32) {
    const int f0 = c0 >> 6, r0 = c0 & 63;
    const int f1 = c1 >> 6, r1 = c1 & 63;
    int g0 = bm + f0 * 16 + (r0 & 15); if (g0 > M - 1) g0 = M - 1;
    int g1 = bm + f1 * 16 + (r1 & 15); if (g1 > M - 1) g1 = M - 1;
    if constexpr (SCALE) { sc0 = rowscale[g0]; sc1 = rowscale[g1]; }
    pa0 = Af32 + (size_t)g0 * K + (r0 >> 4) * 8;
    pa1 = Af32 + (size_t)g1 * K + (r1 >> 4) * 8;
  }

  float4 av[4];
  auto loadA32 = [&](int k0) {
    av[0] = *(const float4*)(pa0 + k0);
    av[1] = *(const float4*)(pa0 + k0 + 4);
    av[2] = *(const float4*)(pa1 + k0);
    av[3] = *(const float4*)(pa1 + k0 + 4);
  };
  auto cvtWriteA = [&](int buf) {
#pragma unroll
    for (int j = 0; j < 2; ++j) {
      const float s = j ? sc1 : sc0;
      const float4 u = av[j * 2], v = av[j * 2 + 1];
      float fv[8] = {u.x, u.y, u.z, u.w, v.x, v.y, v.z, v.w};
      union { _Float16 h[8]; uint4 q; } pk;
#pragma unroll
      for (int i = 0; i < 8; ++i)
        pk.h[i] = (_Float16)(SCALE ? fv[i] * s : fv[i]);
      sA[buf][j ? c1 : c0] = pk.q;  // linear b128 write: conflict-free
    }
  };
  // fp16 A staging: 8 global_load_lds (1KB each), 2 per wave; per-lane gather src,
  // linear LDS dest.
  auto stageA16 = [&](int buf, int k0) {
#pragma unroll
    for (int i = 0; i < 2; ++i) {
      const int f = wid * 2 + i;  // wave-uniform frag 0..7
      int g = bm + f * 16 + (lane & 15); if (g > M - 1) g = M - 1;
      const _Float16* s = Af16 + (size_t)g * K + k0 + (lane >> 4) * 8;
      __builtin_amdgcn_global_load_lds(
          (const __attribute__((address_space(1))) unsigned int*)s,
          (__attribute__((address_space(3))) unsigned int*)&sA[buf][f * 64], 16, 0, 0);
    }
  };
  auto stageB = [&](int buf, int k0) {
#pragma unroll
    for (int i = 0; i < 2; ++i) {
      const int f = wid * 2 + i;
      const _Float16* s = BT + (size_t)(bn + f * 16 + (lane & 15)) * K + k0 + (lane >> 4) * 8;
      __builtin_amdgcn_global_load_lds(
          (const __attribute__((address_space(1))) unsigned int*)s,
          (__attribute__((address_space(3))) unsigned int*)&sB[buf][f * 64], 16, 0, 0);
    }
  };

  f32x4 acc[4][4] = {};
  auto mfmaPhase = [&](int buf) {
    half8 ah[4], bh[4];
#pragma unroll
    for (int m = 0; m < 4; ++m)
      ah[m] = *(const half8*)&sA[buf][(wrow * 4 + m) * 64 + lane];
#pragma unroll
    for (int n = 0; n < 4; ++n)
      bh[n] = *(const half8*)&sB[buf][(wcol * 4 + n) * 64 + lane];
#pragma unroll
    for (int m = 0; m < 4; ++m)
#pragma unroll
      for (int n = 0; n < 4; ++n)
        acc[m][n] = __builtin_amdgcn_mfma_f32_16x16x32_f16(ah[m], bh[n], acc[m][n], 0, 0, 0);
  };

  const int nt = K >> 5;
  if constexpr (AF32) loadA32(0); else stageA16(0, 0);
  stageB(0, 0);
  if constexpr (AF32) cvtWriteA(0);
  __syncthreads();
  for (int t = 0; t < nt; ++t) {
    const int cur = t & 1;
    const bool more = (t + 1 < nt);
    if (more) {
      if constexpr (AF32) loadA32((t + 1) << 5); else stageA16(cur ^ 1, (t + 1) << 5);
      stageB(cur ^ 1, (t + 1) << 5);
    }
    mfmaPhase(cur);
    if (more) { if constexpr (AF32) cvtWriteA(cur ^ 1); }
    __syncthreads();
  }

  // epilogue: C/D frag mapping col=lane&15, row=(lane>>4)*4+reg (m89-verified)
#pragma unroll
  for (int m = 0; m < 4; ++m) {
    const int rb = bm + wrow * 64 + m * 16 + (lane >> 4) * 4;
#pragma unroll
    for (int r = 0; r < 4; ++r) {
      const int gm = rb + r;
      if (gm < M) {
        _Float16* cp = C + (size_t)gm * N + bn + wcol * 64 + (lane & 15);
#pragma unroll
        for (int n = 0; n < 4; ++n) cp[n * 16] = (_Float16)acc[m][n][r];
      }
    }
  }
}

// ---------------- CSR aggregation (one wave per dst node, fp16 gather) ----------------
// out[n] = [oscale *] act( sum_e H[ssrc[e]] * norm_dst[n] + bias )
template <int F, bool RELU, bool OSCALE, bool OUT16>
__launch_bounds__(256)
__global__ void k_agg16(const _Float16* __restrict__ H, const int* __restrict__ row_off,
                        const int* __restrict__ ssrc, const float* __restrict__ norm_dst,
                        const float* __restrict__ bias, const float* __restrict__ oscale,
                        void* __restrict__ outp, int N) {
  int wid = (blockIdx.x * 256 + threadIdx.x) >> 6;
  int lane = threadIdx.x & 63;
  if (wid >= N) return;
  int beg = row_off[wid], end = row_off[wid + 1];
  float nd = norm_dst[wid];

  if constexpr (F == 256) {
    float a0[4] = {}, a1[4] = {}, a2[4] = {}, a3[4] = {};
    int e = beg;
    for (; e + 4 <= end; e += 4) {
      int s0 = ssrc[e], s1 = ssrc[e + 1], s2 = ssrc[e + 2], s3 = ssrc[e + 3];
      half4v v0 = *(const half4v*)(H + (size_t)s0 * 256 + lane * 4);
      half4v v1 = *(const half4v*)(H + (size_t)s1 * 256 + lane * 4);
      half4v v2 = *(const half4v*)(H + (size_t)s2 * 256 + lane * 4);
      half4v v3 = *(const half4v*)(H + (size_t)s3 * 256 + lane * 4);
#pragma unroll
      for (int i = 0; i < 4; ++i) {
        a0[i] += (float)v0[i]; a1[i] += (float)v1[i];
        a2[i] += (float)v2[i]; a3[i] += (float)v3[i];
      }
    }
    for (; e < end; ++e) {
      half4v v = *(const half4v*)(H + (size_t)ssrc[e] * 256 + lane * 4);
#pragma unroll
      for (int i = 0; i < 4; ++i) a0[i] += (float)v[i];
    }
    const float4 bb = *(const float4*)(bias + lane * 4);
    float bv[4] = {bb.x, bb.y, bb.z, bb.w};
    float o[4];
#pragma unroll
    for (int i = 0; i < 4; ++i) {
      o[i] = fmaf(a0[i] + a1[i] + a2[i] + a3[i], nd, bv[i]);
      if (RELU) o[i] = fmaxf(o[i], 0.f);
    }
    if (OSCALE) {
      float os = oscale[wid];
#pragma unroll
      for (int i = 0; i < 4; ++i) o[i] *= os;
    }
    if constexpr (OUT16) {
      union { _Float16 h[4]; uint2 q; } pk;
#pragma unroll
      for (int i = 0; i < 4; ++i) pk.h[i] = (_Float16)o[i];
      *(uint2*)((_Float16*)outp + (size_t)wid * 256 + lane * 4) = pk.q;
    } else {
      *(float4*)((float*)outp + (size_t)wid * 256 + lane * 4) =
          make_float4(o[0], o[1], o[2], o[3]);
    }
  } else {  // F == 128
    float a0[2] = {}, a1[2] = {}, a2[2] = {}, a3[2] = {};
    int e = beg;
    for (; e + 4 <= end; e += 4) {
      int s0 = ssrc[e], s1 = ssrc[e + 1], s2 = ssrc[e + 2], s3 = ssrc[e + 3];
      half2v v0 = *(const half2v*)(H + (size_t)s0 * 128 + lane * 2);
      half2v v1 = *(const half2v*)(H + (size_t)s1 * 128 + lane * 2);
      half2v v2 = *(const half2v*)(H + (size_t)s2 * 128 + lane * 2);
      half2v v3 = *(const half2v*)(H + (size_t)s3 * 128 + lane * 2);
#pragma unroll
      for (int i = 0; i < 2; ++i) {
        a0[i] += (float)v0[i]; a1[i] += (float)v1[i];
        a2[i] += (float)v2[i]; a3[i] += (float)v3[i];
      }
    }
    for (; e < end; ++e) {
      half2v v = *(const half2v*)(H + (size_t)ssrc[e] * 128 + lane * 2);
#pragma unroll
      for (int i = 0; i < 2; ++i) a0[i] += (float)v[i];
    }
    const float2 bb = *(const float2*)(bias + lane * 2);
    float bv[2] = {bb.x, bb.y};
    float o[2];
#pragma unroll
    for (int i = 0; i < 2; ++i) {
      o[i] = fmaf(a0[i] + a1[i] + a2[i] + a3[i], nd, bv[i]);
      if (RELU) o[i] = fmaxf(o[i], 0.f);
    }
    if (OSCALE) {
      float os = oscale[wid];
#pragma unroll
      for (int i = 0; i < 2; ++i) o[i] *= os;
    }
    if constexpr (OUT16) {
      union { _Float16 h[2]; unsigned q; } pk;
      pk.h[0] = (_Float16)o[0]; pk.h[1] = (_Float16)o[1];
      *(unsigned*)((_Float16*)outp + (size_t)wid * 128 + lane * 2) = pk.q;
    } else {
      *(float2*)((float*)outp + (size_t)wid * 128 + lane * 2) = make_float2(o[0], o[1]);
    }
  }
}

// ---------------- launch ----------------

extern "C" void kernel_launch(void* const* d_in, const int* in_sizes, int n_in,
                              void* d_out, int out_size, void* d_ws, size_t ws_size,
                              hipStream_t stream) {
  const float* X  = (const float*)d_in[0];
  const float* W1 = (const float*)d_in[1];
  const float* b1 = (const float*)d_in[2];
  const float* W2 = (const float*)d_in[3];
  const float* b2 = (const float*)d_in[4];
  const int* src  = (const int*)d_in[5];
  const int* dst  = (const int*)d_in[6];
  float* out = (float*)d_out;

  char* p = (char*)d_ws;
  auto alloc = [&](size_t bytes) -> char* {
    char* r = p;
    p += (bytes + 255) & ~(size_t)255;
    return r;
  };
  _Float16* H1pre  = (_Float16*)alloc((size_t)NN * HID * 2);   // layer-1 pre-agg
  _Float16* H1post = (_Float16*)alloc((size_t)NN * HID * 2);   // relu(...)*nsrc
  _Float16* H2pre  = H1pre;                                    // reuse
  _Float16* W1T = (_Float16*)alloc((size_t)HID * IN_F * 2);
  _Float16* W2T = (_Float16*)alloc((size_t)OUTF * HID * 2);
  int* deg_out  = (int*)alloc((size_t)NN * 4);
  int* deg_in   = (int*)alloc((size_t)NN * 4);
  int* cursor   = (int*)alloc((size_t)NN * 4);
  int* row_off  = (int*)alloc((size_t)(NN + 1) * 4);
  int* bsums    = (int*)alloc(512);
  float* nsrc   = (float*)alloc((size_t)NN * 4);
  float* ndst   = (float*)alloc((size_t)NN * 4);
  int* ssrc     = (int*)alloc((size_t)NE * 4);

  hipMemsetAsync(deg_out, 0, (size_t)((char*)row_off - (char*)deg_out), stream);

  k_degree<<<(NE + 255) / 256, 256, 0, stream>>>(src, dst, deg_out, deg_in, NE);
  k_norm<<<(NN + 255) / 256, 256, 0, stream>>>(deg_out, deg_in, nsrc, ndst, NN);

  int nb = (NN + 511) / 512;
  k_scan1<<<nb, 512, 0, stream>>>(deg_in, row_off, bsums, NN);
  k_scan2<<<1, 128, 0, stream>>>(bsums, nb);
  k_scan3<<<(NN + 255) / 256, 256, 0, stream>>>(row_off, bsums, NN, NE);
  k_fill<<<(NE + 255) / 256, 256, 0, stream>>>(src, dst, row_off, cursor, ssrc, NE);

  k_convW<<<(IN_F * HID + 255) / 256, 256, 0, stream>>>(W1, W1T, IN_F, HID);
  k_convW<<<(HID * OUTF + 255) / 256, 256, 0, stream>>>(W2, W2T, HID, OUTF);

  // layer 1: H1pre = f16[(X*nsrc)@W1]; H1post = f16[relu(agg*ndst + b1)*nsrc]
  dim3 g1((NN + 127) / 128, HID / 128);
  k_gemm_f16<true, true><<<g1, 256, 0, stream>>>(X, W1T, nsrc, H1pre, NN, HID, IN_F);
  k_agg16<256, true, true, true><<<(NN * 64 + 255) / 256, 256, 0, stream>>>(
      H1pre, row_off, ssrc, ndst, b1, nsrc, H1post, NN);

  // layer 2: H2pre = f16[H1post@W2]; out = agg*ndst + b2 (fp32)
  dim3 g2((NN + 127) / 128, OUTF / 128);
  k_gemm_f16<false, false><<<g2, 256, 0, stream>>>(H1post, W2T, nullptr, H2pre, NN, OUTF, HID);
  k_agg16<128, false, false, false><<<(NN * 64 + 255) / 256, 256, 0, stream>>>(
      H2pre, row_off, ssrc, ndst, b2, nullptr, out, NN);
}